// Round 9
// baseline (1964.256 us; speedup 1.0000x reference)
//
#include <hip/hip_runtime.h>

#define T_STEPS 64
#define NN 1024
#define BKC 128

typedef __bf16 bf16x8 __attribute__((ext_vector_type(8)));
typedef float f32x4 __attribute__((ext_vector_type(4)));

__device__ __forceinline__ float fast_tanh(float z) {
    z = fminf(15.f, fmaxf(-15.f, z));
    const float t = __builtin_amdgcn_exp2f(z * 2.8853900817779268f);  // e^{2z}
    return (t - 1.f) * __builtin_amdgcn_rcpf(t + 1.f);
}

// load one kb batch of fragments (16 x b128 from L2/L3)
#define LOAD_KB(kb, ah, al, bh, bl)                                         \
    _Pragma("unroll")                                                       \
    for (int p = 0; p < 4; ++p) {                                           \
        ah[p] = *(const bf16x8*)(Abase + (kb) * 4096 + p * 512);            \
        al[p] = *(const bf16x8*)(Abase + (kb) * 4096 + 2048 + p * 512);     \
    }                                                                       \
    _Pragma("unroll")                                                       \
    for (int c = 0; c < 4; ++c) {                                           \
        bh[c] = *(const bf16x8*)(Bbaseh + (kb) * 512 + c * 16384);          \
        bl[c] = *(const bf16x8*)(Bbasel + (kb) * 512 + c * 16384);          \
    }

// 48 MFMAs (3-term split product) on one kb batch
#define MFMA_KB(ah, al, bh, bl)                                             \
    _Pragma("unroll")                                                       \
    for (int p = 0; p < 4; ++p)                                             \
        _Pragma("unroll")                                                   \
        for (int c = 0; c < 4; ++c) {                                       \
            acc[p][c] = __builtin_amdgcn_mfma_f32_16x16x32_bf16(ah[p], bh[c], acc[p][c], 0, 0, 0); \
            acc[p][c] = __builtin_amdgcn_mfma_f32_16x16x32_bf16(al[p], bh[c], acc[p][c], 0, 0, 0); \
            acc[p][c] = __builtin_amdgcn_mfma_f32_16x16x32_bf16(ah[p], bl[c], acc[p][c], 0, 0, 0); \
        }

// ===========================================================================
// Persistent rollout, 256 blocks x 512 thr, 1 block/CU (151 KB LDS). All 64
// steps in-kernel; R8's proven step body. Grid barrier per step with the
// FIXED protocol: fetch_add(RELEASE) -> RELAXED spin (no cache ops per poll;
// R7's acquire-per-poll emitted a whole-L2 buffer_inv per iteration = 45
// us/step) -> single fence(ACQUIRE) (one invL2/block, same as any kernel
// dispatch does). SX state in padded LDS (keeps VGPR budget for the 2-deep
// register pipeline). K stays inside the block (R4 lesson).
// ===========================================================================
__global__ __launch_bounds__(512, 1) void rollout(
    const __bf16* __restrict__ AF,
    __bf16* __restrict__ WF0h, __bf16* __restrict__ WF0l,
    __bf16* __restrict__ WF1h, __bf16* __restrict__ WF1l,
    const float* __restrict__ SX,
    float* __restrict__ x_traj, float* __restrict__ u_traj,
    const float* __restrict__ H1, const float* __restrict__ H2,
    unsigned* __restrict__ ctr)
{
    __shared__ __align__(16) float dumps[8][4096];   // 128 KB
    __shared__ float h1s[512];
    __shared__ float h2s[128];
    __shared__ float sxs[256 * 17];                  // SX state, pad 17 (bank-free)

    const int tid  = threadIdx.x;
    const int lane = tid & 63;
    const int w    = tid >> 6;                 // wave 0..7 (K-split)

    h1s[tid & 511] = H1[tid & 511];
    if (tid < 128) h2s[tid] = H2[tid];

    // XCD-aware: each XCD gets 8 nb values x 4 cb -> 2MB A slice L2-resident
    const int l = blockIdx.x;
    const int xcd = l & 7, j = l >> 3;
    const int nb = xcd * 8 + (j & 7);          // 0..63
    const int cb = j >> 3;                     // 0..3

    const __bf16* Abase = AF + ((size_t)nb * 32 + w * 4) * 4096 + lane * 8;
    const size_t boff = ((size_t)(cb * 4) * 32 + w * 4) * 512 + lane * 8;

    // epilogue constants
    const int i   = tid & 15;
    const int bl2 = (tid >> 4) & 15;
    const int n   = nb * 16 + i;
    const int bg  = cb * 16 + bl2;
    const int rc  = bl2 >> 2;
    const int lidx = ((i >> 2) << 4) + (bl2 & 3) * 4;
    const int rr  = i & 3;
    const int kblkw = n >> 5;
    const int lhi = ((n >> 3) & 3) << 4;
    const int jw  = n & 7;

    // seed SX state into LDS
    if (tid < 256) {
        #pragma unroll
        for (int p = 0; p < 4; ++p) {
            const f32x4 v = *(const f32x4*)(SX + (size_t)(p * NN + n) * 256 + bg * 4);
            #pragma unroll
            for (int q = 0; q < 4; ++q) sxs[tid * 17 + p * 4 + q] = v[q];
        }
    }
    __syncthreads();

    unsigned bar = 0;

    #pragma unroll 1
    for (int t = 0; t < T_STEPS; ++t) {
        const __bf16* Bbaseh = ((t & 1) ? WF1h : WF0h) + boff;
        const __bf16* Bbasel = ((t & 1) ? WF1l : WF0l) + boff;
        __bf16* Woh = (t & 1) ? WF0h : WF1h;
        __bf16* Wol = (t & 1) ? WF0l : WF1l;

        // ================= GEMM: 2-deep register pipeline (R8) =================
        f32x4 acc[4][4];
        #pragma unroll
        for (int p = 0; p < 4; ++p)
            #pragma unroll
            for (int c = 0; c < 4; ++c)
                acc[p][c] = (f32x4){0.f, 0.f, 0.f, 0.f};

        bf16x8 aAh[4], aAl[4], aBh[4], aBl[4];
        bf16x8 bAh[4], bAl[4], bBh[4], bBl[4];

        LOAD_KB(0, aAh, aAl, aBh, aBl)
        LOAD_KB(1, bAh, bAl, bBh, bBl)
        MFMA_KB(aAh, aAl, aBh, aBl)
        LOAD_KB(2, aAh, aAl, aBh, aBl)
        MFMA_KB(bAh, bAl, bBh, bBl)
        LOAD_KB(3, bAh, bAl, bBh, bBl)
        MFMA_KB(aAh, aAl, aBh, aBl)
        MFMA_KB(bAh, bAl, bBh, bBl)

        // ---- combine wave partials (conflict-free two-pass reduce, R8) ----
        #pragma unroll
        for (int p = 0; p < 4; ++p)
            #pragma unroll
            for (int c = 0; c < 4; ++c)
                *(f32x4*)&dumps[w][(p * 4 + c) * 256 + lane * 4] = acc[p][c];
        __syncthreads();
        #pragma unroll
        for (int pass = 0; pass < 2; ++pass) {
            const int pos = pass * 2048 + tid * 4;
            f32x4 s = *(const f32x4*)&dumps[0][pos];
            #pragma unroll
            for (int w2 = 1; w2 < 8; ++w2)
                s += *(const f32x4*)&dumps[w2][pos];
            *(f32x4*)&dumps[0][pos] = s;
        }
        __syncthreads();

        // ---- epilogue on first 256 threads ----
        if (tid < 256) {
            float nv[4][4];
            f32x4 xv, uv;
            #pragma unroll
            for (int p = 0; p < 4; ++p) {
                f32x4 inc;
                #pragma unroll
                for (int q = 0; q < 4; ++q)
                    inc[q] = dumps[0][(p * 4 + rc) * 256 + (lidx + q) * 4 + rr];
                #pragma unroll
                for (int q = 0; q < 4; ++q) {
                    float nw = fmaf(0.1f, inc[q], sxs[tid * 17 + p * 4 + q]);
                    sxs[tid * 17 + p * 4 + q] = nw;
                    nv[p][q] = nw;
                }
                if (p == 0) {
                    #pragma unroll
                    for (int q = 0; q < 4; ++q) { xv[q] = nv[0][q]; uv[q] = inc[q]; }
                }
            }
            *(f32x4*)(x_traj + ((size_t)bg * (T_STEPS + 1) + t + 1) * 4096 + n * 4) = xv;
            *(f32x4*)(u_traj + ((size_t)bg * T_STEPS + t) * 4096 + n * 4) = uv;

            float w4[4] = {0.f, 0.f, 0.f, 0.f};
            #pragma unroll 4
            for (int f = 0; f < 32; ++f) {
                float z = 0.f;
                #pragma unroll
                for (int k = 0; k < 4; ++k)
                    #pragma unroll
                    for (int q = 0; q < 4; ++q)
                        z = fmaf(nv[k][q], h1s[(k * 4 + q) * 32 + f], z);
                z = fast_tanh(z);
                #pragma unroll
                for (int q = 0; q < 4; ++q) w4[q] = fmaf(z, h2s[f * 4 + q], w4[q]);
            }
            #pragma unroll
            for (int q = 0; q < 4; ++q) {
                const int col = bg * 4 + q;
                const size_t o = ((size_t)(col >> 4) * 32 + kblkw) * 512 + ((col & 15) + lhi) * 8 + jw;
                const __bf16 h = (__bf16)w4[q];
                Woh[o] = h;
                Wol[o] = (__bf16)(w4[q] - (float)h);
            }
        }

        // ======= grid barrier: release-add, RELAXED spin, single acquire =======
        if (t < T_STEPS - 1) {
            __syncthreads();   // all W writes issued & drained (vmcnt before barrier)
            if (tid == 0) {
                __hip_atomic_fetch_add(ctr, 1u, __ATOMIC_RELEASE, __HIP_MEMORY_SCOPE_AGENT);
                const unsigned tgt = bar + 256;
                while (__hip_atomic_load(ctr, __ATOMIC_RELAXED, __HIP_MEMORY_SCOPE_AGENT) < tgt)
                    __builtin_amdgcn_s_sleep(4);
                __builtin_amdgcn_fence(__ATOMIC_ACQUIRE, "agent");
            }
            bar += 256;
            __syncthreads();
        }
    }
}

// ===========================================================================
// Setup kernels (proven R2-R8, unchanged)
// ===========================================================================
template<int MODE>
__global__ __launch_bounds__(256) void gemm_core(
    const __bf16* __restrict__ Ah, const __bf16* __restrict__ Al,
    const __bf16* __restrict__ Bh, const __bf16* __restrict__ Bl,
    __bf16* __restrict__ Oh, __bf16* __restrict__ Ol,
    float* __restrict__ SX)
{
    const int cb = blockIdx.x, nb = blockIdx.y;
    const int c0 = cb * 64;

    __shared__ char sA[2][16384];
    __shared__ char sB[2][16384];

    const int tid = threadIdx.x;
    const int lane = tid & 63;
    const int wid  = tid >> 6;
    const int wr = wid >> 1, wc = wid & 1;

    f32x4 acc[2][2];
    #pragma unroll
    for (int a = 0; a < 2; ++a)
        #pragma unroll
        for (int b = 0; b < 2; ++b)
            acc[a][b] = (f32x4){0.f, 0.f, 0.f, 0.f};

    for (int ch = 0; ch < 1024 / BKC; ++ch) {
        const int k0 = ch * BKC;
        __syncthreads();
        #pragma unroll
        for (int jj = 0; jj < 4; ++jj) {
            const int idx = jj * 256 + tid;
            const int r = idx >> 4, s = idx & 15;
            const int d = (r << 8) + ((s << 4) ^ ((r & 15) << 4));
            const int gA = nb * 64 + r;
            {
                const size_t off = (size_t)gA * 1024 + k0 + s * 8;
                *(uint4*)(sA[0] + d) = *(const uint4*)(Ah + off);
                *(uint4*)(sA[1] + d) = *(const uint4*)(Al + off);
            }
            {
                const size_t off = (size_t)(c0 + r) * 1024 + k0 + s * 8;
                *(uint4*)(sB[0] + d) = *(const uint4*)(Bh + off);
                *(uint4*)(sB[1] + d) = *(const uint4*)(Bl + off);
            }
        }
        __syncthreads();
        #pragma unroll
        for (int ks = 0; ks < 4; ++ks) {
            const int kb = ks * 64 + ((lane >> 4) << 4);
            bf16x8 afr[2][2], bfr[2][2];
            #pragma unroll
            for (int rt = 0; rt < 2; ++rt) {
                const int row = wr * 32 + rt * 16 + (lane & 15);
                const int d = (row << 8) + (kb ^ ((row & 15) << 4));
                afr[rt][0] = *(const bf16x8*)(sA[0] + d);
                afr[rt][1] = *(const bf16x8*)(sA[1] + d);
            }
            #pragma unroll
            for (int ct = 0; ct < 2; ++ct) {
                const int row = wc * 32 + ct * 16 + (lane & 15);
                const int d = (row << 8) + (kb ^ ((row & 15) << 4));
                bfr[ct][0] = *(const bf16x8*)(sB[0] + d);
                bfr[ct][1] = *(const bf16x8*)(sB[1] + d);
            }
            #pragma unroll
            for (int rt = 0; rt < 2; ++rt)
                #pragma unroll
                for (int ct = 0; ct < 2; ++ct) {
                    acc[rt][ct] = __builtin_amdgcn_mfma_f32_16x16x32_bf16(afr[rt][0], bfr[ct][0], acc[rt][ct], 0, 0, 0);
                    acc[rt][ct] = __builtin_amdgcn_mfma_f32_16x16x32_bf16(afr[rt][0], bfr[ct][1], acc[rt][ct], 0, 0, 0);
                    acc[rt][ct] = __builtin_amdgcn_mfma_f32_16x16x32_bf16(afr[rt][1], bfr[ct][0], acc[rt][ct], 0, 0, 0);
                }
        }
    }

    #pragma unroll
    for (int rt = 0; rt < 2; ++rt)
        #pragma unroll
        for (int ct = 0; ct < 2; ++ct)
            #pragma unroll
            for (int r = 0; r < 4; ++r) {
                const int row = wr * 32 + rt * 16 + ((lane >> 4) << 2) + r;
                const int col = wc * 32 + ct * 16 + (lane & 15);
                const float v = acc[rt][ct][r];
                if (MODE == 0) {
                    const size_t o = (size_t)(nb * 64 + row) * 1024 + c0 + col;
                    const __bf16 h = (__bf16)v;
                    Oh[o] = h;
                    Ol[o] = (__bf16)(v - (float)h);
                } else {
                    SX[(size_t)(nb * 64 + row) * 256 + c0 + col] = v;
                }
            }
}

__global__ __launch_bounds__(1024) void split_S(const float* __restrict__ S,
    __bf16* __restrict__ Ah, __bf16* __restrict__ Al,
    __bf16* __restrict__ STh, __bf16* __restrict__ STl)
{
    __shared__ float tile[32][33];
    const int tx = threadIdx.x & 31, ty = threadIdx.x >> 5;
    const int r0 = blockIdx.y * 32, c0 = blockIdx.x * 32;
    const float v = S[(size_t)(r0 + ty) * 1024 + c0 + tx];
    tile[ty][tx] = v;
    {
        const __bf16 h = (__bf16)v;
        const size_t o = (size_t)(r0 + ty) * 1024 + c0 + tx;
        Ah[o] = h; Al[o] = (__bf16)(v - (float)h);
    }
    __syncthreads();
    const float wv = tile[tx][ty];
    const __bf16 h = (__bf16)wv;
    const size_t o = (size_t)(c0 + ty) * 1024 + r0 + tx;
    STh[o] = h; STl[o] = (__bf16)(wv - (float)h);
}

// row-major split planes -> AF fragment layout
__global__ __launch_bounds__(256) void repackAF2(const __bf16* __restrict__ rmh,
    const __bf16* __restrict__ rml, __bf16* __restrict__ AF)
{
    const int g = blockIdx.x * 256 + threadIdx.x;
    const int row = g >> 7;
    const int k0 = (g & 127) * 8;
    const int p = row >> 10, n = row & 1023;
    const int nb = n >> 4, i = n & 15;
    const int kblk = k0 >> 5, khi = (k0 >> 3) & 3;
    const size_t off = ((size_t)nb * 32 + kblk) * 4096 + p * 512 + (i + 16 * khi) * 8;
    *(bf16x8*)(AF + off)        = *(const bf16x8*)(rmh + (size_t)row * 1024 + k0);
    *(bf16x8*)(AF + off + 2048) = *(const bf16x8*)(rml + (size_t)row * 1024 + k0);
}

__global__ __launch_bounds__(256) void init_x0(const float* __restrict__ x0,
    float* __restrict__ SX, float* __restrict__ x_traj,
    __bf16* __restrict__ X0Th, __bf16* __restrict__ X0Tl)
{
    const int g = blockIdx.x * 256 + threadIdx.x;
    const int b = g >> 10, n = g & 1023;
    const f32x4 v = *(const f32x4*)(x0 + (size_t)g * 4);
    *(f32x4*)(SX + (size_t)n * 256 + b * 4) = v;
    *(f32x4*)(x_traj + (size_t)b * ((T_STEPS + 1) * 4096) + n * 4) = v;
    #pragma unroll
    for (int p = 0; p < 4; ++p) {
        const __bf16 h = (__bf16)v[p];
        const size_t o = (size_t)(b * 4 + p) * 1024 + n;
        X0Th[o] = h; X0Tl[o] = (__bf16)(v[p] - (float)h);
    }
}

__global__ __launch_bounds__(256) void w0_kernel(const float* __restrict__ SX,
    const float* __restrict__ H1, const float* __restrict__ H2,
    __bf16* __restrict__ WFh, __bf16* __restrict__ WFl)
{
    __shared__ float h1s[512], h2s[128];
    const int tid = threadIdx.x;
    for (int i2 = tid; i2 < 512; i2 += 256) h1s[i2] = H1[i2];
    if (tid < 128) h2s[tid] = H2[tid];
    __syncthreads();
    const int g = blockIdx.x * 256 + tid;
    const int b = g >> 10, n = g & 1023;
    float sx[16];
    #pragma unroll
    for (int k = 0; k < 4; ++k) {
        const f32x4 v = *(const f32x4*)(SX + (size_t)(k * NN + n) * 256 + b * 4);
        #pragma unroll
        for (int q = 0; q < 4; ++q) sx[k * 4 + q] = v[q];
    }
    float w4[4] = {0.f, 0.f, 0.f, 0.f};
    #pragma unroll 4
    for (int f = 0; f < 32; ++f) {
        float z = 0.f;
        #pragma unroll
        for (int kp = 0; kp < 16; ++kp) z = fmaf(sx[kp], h1s[kp * 32 + f], z);
        z = fast_tanh(z);
        #pragma unroll
        for (int q = 0; q < 4; ++q) w4[q] = fmaf(z, h2s[f * 4 + q], w4[q]);
    }
    const int kblkw = n >> 5;
    const int lhi = ((n >> 3) & 3) << 4;
    const int jw = n & 7;
    #pragma unroll
    for (int q = 0; q < 4; ++q) {
        const int col = b * 4 + q;
        const size_t o = ((size_t)(col >> 4) * 32 + kblkw) * 512 + ((col & 15) + lhi) * 8 + jw;
        const __bf16 h = (__bf16)w4[q];
        WFh[o] = h;
        WFl[o] = (__bf16)(w4[q] - (float)h);
    }
}

extern "C" void kernel_launch(void* const* d_in, const int* in_sizes, int n_in,
                              void* d_out, int out_size, void* d_ws, size_t ws_size,
                              hipStream_t stream)
{
    const float* x0 = (const float*)d_in[0];
    const float* S  = (const float*)d_in[1];
    const float* H1 = (const float*)d_in[2];
    const float* H2 = (const float*)d_in[3];

    float* x_traj = (float*)d_out;
    float* u_traj = x_traj + (size_t)64 * (T_STEPS + 1) * NN * 4;

    // workspace carve (38 MB)
    char* w = (char*)d_ws;
    __bf16* Ah_rm = (__bf16*)(w);                    // 8 MB [setup only; dead at rollout]
    __bf16* Al_rm = (__bf16*)(w + (8u << 20));       // 8 MB [setup only]
    __bf16* AF    = (__bf16*)(w + (16u << 20));      // 16 MB fragment-order A
    float*  SX    = (float*) (w + (32u << 20));      // 4 MB (seed only)
    __bf16* WF0h  = (__bf16*)(w + (36u << 20));                  // 512 KB
    __bf16* WF0l  = (__bf16*)(w + (36u << 20) + (512u << 10));   // 512 KB
    __bf16* WF1h  = (__bf16*)(w + (37u << 20));                  // 512 KB
    __bf16* WF1l  = (__bf16*)(w + (37u << 20) + (512u << 10));   // 512 KB
    unsigned* ctr = (unsigned*)(w + (4u << 20));     // inside Ah_rm, dead at rollout
    // setup-only aliases
    __bf16* STh   = AF;                              // dead before repackAF2
    __bf16* STl   = AF + (size_t)1024 * 1024;
    __bf16* X0Th  = WF1h;                            // dead before step 0 writes
    __bf16* X0Tl  = WF1l;

    dim3 blk(256);

    // 1) split S -> row-major split planes + S^T split planes
    split_S<<<dim3(32, 32), 1024, 0, stream>>>(S, Ah_rm, Al_rm, STh, STl);

    // 2) power chain: S^{j+1} = S^j @ S (full 3-term precision)
    for (int jj = 1; jj <= 3; ++jj) {
        gemm_core<0><<<dim3(16, 16), blk, 0, stream>>>(
            Ah_rm + (size_t)(jj - 1) * 1024 * 1024, Al_rm + (size_t)(jj - 1) * 1024 * 1024,
            STh, STl,
            Ah_rm + (size_t)jj * 1024 * 1024, Al_rm + (size_t)jj * 1024 * 1024, nullptr);
    }

    // 3) SX_0 = x0, x_traj[:,0], x0^T split planes (into WF1 aliases)
    init_x0<<<dim3(256), blk, 0, stream>>>(x0, SX, x_traj, X0Th, X0Tl);

    // 4) SX_{1..3} = [S;S^2;S^3] @ x0
    gemm_core<1><<<dim3(4, 48), blk, 0, stream>>>(
        Ah_rm, Al_rm, X0Th, X0Tl, nullptr, nullptr, SX + (size_t)1024 * 256);

    // 5) repack row-major -> fragment layout (clobbers ST alias; after chain)
    repackAF2<<<dim3(2048), blk, 0, stream>>>(Ah_rm, Al_rm, AF);

    // 6) W_0 -> WF0 planes
    w0_kernel<<<dim3(256), blk, 0, stream>>>(SX, H1, H2, WF0h, WF0l);

    // 7) zero barrier counter (Ah_rm dead), persistent rollout (all 64 steps)
    hipMemsetAsync(ctr, 0, 256, stream);
    rollout<<<dim3(256), dim3(512), 0, stream>>>(
        AF, WF0h, WF0l, WF1h, WF1l, SX, x_traj, u_traj, H1, H2, ctr);
}

// Round 10
// 1288.830 us; speedup vs baseline: 1.5241x; 1.5241x over previous
//
#include <hip/hip_runtime.h>

#define T_STEPS 64
#define NN 1024
#define BKC 128

typedef __bf16 bf16x8 __attribute__((ext_vector_type(8)));
typedef float f32x4 __attribute__((ext_vector_type(4)));

__device__ __forceinline__ float fast_tanh(float z) {
    z = fminf(15.f, fmaxf(-15.f, z));
    const float t = __builtin_amdgcn_exp2f(z * 2.8853900817779268f);  // e^{2z}
    return (t - 1.f) * __builtin_amdgcn_rcpf(t + 1.f);
}

__device__ __forceinline__ void nt_store4(float* p, f32x4 v) {
    __builtin_nontemporal_store(v, (f32x4*)p);
}

// ===========================================================================
// Per-step fused kernel (R10). 256 blocks x 512 thr (8 waves).
// Block (nb, cb): C tile = (4 powers x 16 nodes) x 64 cols, K=1024.
// Wave split: ks (K half, 2) x cq (col quarter, 4)  -- each wave computes a
// 64x16 partial over K=512. 4x smaller LDS dump than R8's 8-way K split
// (34 KB vs 128 KB round-trip). A/B read global->VGPR in fragment order with
// a 2-deep register pipeline (compile-time buffer indices). x/u trajectories
// written NONTEMPORAL so the 2 MB/step of dead writes don't evict A from L2
// (R9 counters: 3.8 MB/step A refetch). Kernel boundary = grid sync (R4/R7/
// R9 lesson: in-kernel cross-XCD barriers cost >=20 us/step).
// ===========================================================================
__global__ __launch_bounds__(512, 1) void step_kernel(
    const __bf16* __restrict__ AF,
    const __bf16* __restrict__ WFh, const __bf16* __restrict__ WFl,
    __bf16* __restrict__ WFoh, __bf16* __restrict__ WFol,
    float* __restrict__ SX, float* __restrict__ x_traj, float* __restrict__ u_traj,
    const float* __restrict__ H1, const float* __restrict__ H2, int t)
{
    __shared__ __align__(16) float dumps[2][64][68];   // 34 KB, padded rows
    __shared__ float h1s[512];
    __shared__ float h2s[128];

    const int tid  = threadIdx.x;
    const int lane = tid & 63;
    const int w    = tid >> 6;
    const int ks   = w >> 2;           // K half (0/1)
    const int cq   = w & 3;            // col quarter (0..3)

    h1s[tid & 511] = H1[tid & 511];
    if (tid < 128) h2s[tid] = H2[tid];

    // XCD-aware: each XCD gets 8 nb values x 4 cb -> 2MB A slice L2-resident
    const int l = blockIdx.x;
    const int xcd = l & 7, j = l >> 3;
    const int nb = xcd * 8 + (j & 7);  // 0..63
    const int cb = j >> 3;             // 0..3

    // fragment-order bases:
    //   AF[(nb*32+kblk)*4096 + plane*2048 + p*512 + lane*8], kblk = ks*16+kb
    //   WF[(colblk*32+kblk)*512 + lane*8],  colblk = cb*4+cq
    const __bf16* Abase  = AF  + ((size_t)nb * 32 + ks * 16) * 4096 + lane * 8;
    const __bf16* Bbaseh = WFh + ((size_t)(cb * 4 + cq) * 32 + ks * 16) * 512 + lane * 8;
    const __bf16* Bbasel = WFl + ((size_t)(cb * 4 + cq) * 32 + ks * 16) * 512 + lane * 8;

    f32x4 acc[4];
    #pragma unroll
    for (int p = 0; p < 4; ++p) acc[p] = (f32x4){0.f, 0.f, 0.f, 0.f};

    // ---- 2-deep register pipeline over 16 kb iterations (indices fold) ----
    bf16x8 ah[2][4], al[2][4], bh[2], bl[2];
    #pragma unroll
    for (int p = 0; p < 4; ++p) {
        ah[0][p] = *(const bf16x8*)(Abase + p * 512);
        al[0][p] = *(const bf16x8*)(Abase + 2048 + p * 512);
    }
    bh[0] = *(const bf16x8*)(Bbaseh);
    bl[0] = *(const bf16x8*)(Bbasel);

    #pragma unroll
    for (int kb = 0; kb < 16; ++kb) {
        const int cur = kb & 1, nxt = cur ^ 1;
        if (kb < 15) {
            #pragma unroll
            for (int p = 0; p < 4; ++p) {
                ah[nxt][p] = *(const bf16x8*)(Abase + (kb + 1) * 4096 + p * 512);
                al[nxt][p] = *(const bf16x8*)(Abase + (kb + 1) * 4096 + 2048 + p * 512);
            }
            bh[nxt] = *(const bf16x8*)(Bbaseh + (kb + 1) * 512);
            bl[nxt] = *(const bf16x8*)(Bbasel + (kb + 1) * 512);
        }
        #pragma unroll
        for (int p = 0; p < 4; ++p) {
            acc[p] = __builtin_amdgcn_mfma_f32_16x16x32_bf16(ah[cur][p], bh[cur], acc[p], 0, 0, 0);
            acc[p] = __builtin_amdgcn_mfma_f32_16x16x32_bf16(al[cur][p], bh[cur], acc[p], 0, 0, 0);
            acc[p] = __builtin_amdgcn_mfma_f32_16x16x32_bf16(ah[cur][p], bl[cur], acc[p], 0, 0, 0);
        }
    }

    // ---- dump 64x16 partial into (row, col) layout ----
    {
        const int rbase = (lane >> 4) * 4;
        const int c = cq * 16 + (lane & 15);
        #pragma unroll
        for (int p = 0; p < 4; ++p)
            #pragma unroll
            for (int r = 0; r < 4; ++r)
                dumps[ks][p * 16 + rbase + r][c] = acc[p][r];
    }
    __syncthreads();
    // ---- 2-way reduce, vectorized, conflict-free ----
    {
        const int row = tid >> 3, cg = (tid & 7) * 8;
        f32x4 s0 = *(const f32x4*)&dumps[0][row][cg];
        f32x4 s1 = *(const f32x4*)&dumps[0][row][cg + 4];
        s0 += *(const f32x4*)&dumps[1][row][cg];
        s1 += *(const f32x4*)&dumps[1][row][cg + 4];
        *(f32x4*)&dumps[0][row][cg]     = s0;
        *(f32x4*)&dumps[0][row][cg + 4] = s1;
    }
    __syncthreads();

    // ---- epilogue on first 256 threads ----
    if (tid < 256) {
        const int i   = tid & 15;      // node-local
        const int bl2 = tid >> 4;      // batch-local (0..15)
        const int n   = nb * 16 + i;
        const int bg  = cb * 16 + bl2;

        float nv[4][4];
        f32x4 xv, uv;
        #pragma unroll
        for (int p = 0; p < 4; ++p) {
            const f32x4 inc = *(const f32x4*)&dumps[0][p * 16 + i][bl2 * 4];
            const size_t so = (size_t)(p * NN + n) * 256 + bg * 4;
            f32x4 old = *(const f32x4*)(SX + so);
            f32x4 nw;
            #pragma unroll
            for (int q = 0; q < 4; ++q) nw[q] = fmaf(0.1f, inc[q], old[q]);
            *(f32x4*)(SX + so) = nw;
            #pragma unroll
            for (int q = 0; q < 4; ++q) nv[p][q] = nw[q];
            if (p == 0) { xv = nw; uv = inc; }
        }
        nt_store4(x_traj + ((size_t)bg * (T_STEPS + 1) + t + 1) * 4096 + n * 4, xv);
        nt_store4(u_traj + ((size_t)bg * T_STEPS + t) * 4096 + n * 4, uv);

        float w4[4] = {0.f, 0.f, 0.f, 0.f};
        #pragma unroll 4
        for (int f = 0; f < 32; ++f) {
            float z = 0.f;
            #pragma unroll
            for (int k = 0; k < 4; ++k)
                #pragma unroll
                for (int q = 0; q < 4; ++q)
                    z = fmaf(nv[k][q], h1s[(k * 4 + q) * 32 + f], z);
            z = fast_tanh(z);
            #pragma unroll
            for (int q = 0; q < 4; ++q) w4[q] = fmaf(z, h2s[f * 4 + q], w4[q]);
        }
        // W -> fragment order, split hi/lo planes
        const int kblkw = n >> 5;
        const int lhi = ((n >> 3) & 3) << 4;
        const int jw = n & 7;
        #pragma unroll
        for (int q = 0; q < 4; ++q) {
            const int col = bg * 4 + q;
            const size_t o = ((size_t)(col >> 4) * 32 + kblkw) * 512 + ((col & 15) + lhi) * 8 + jw;
            const __bf16 h = (__bf16)w4[q];
            WFoh[o] = h;
            WFol[o] = (__bf16)(w4[q] - (float)h);
        }
    }
}

// ===========================================================================
// Setup kernels (proven R2-R8, unchanged)
// ===========================================================================
template<int MODE>
__global__ __launch_bounds__(256) void gemm_core(
    const __bf16* __restrict__ Ah, const __bf16* __restrict__ Al,
    const __bf16* __restrict__ Bh, const __bf16* __restrict__ Bl,
    __bf16* __restrict__ Oh, __bf16* __restrict__ Ol,
    float* __restrict__ SX)
{
    const int cb = blockIdx.x, nb = blockIdx.y;
    const int c0 = cb * 64;

    __shared__ char sA[2][16384];
    __shared__ char sB[2][16384];

    const int tid = threadIdx.x;
    const int lane = tid & 63;
    const int wid  = tid >> 6;
    const int wr = wid >> 1, wc = wid & 1;

    f32x4 acc[2][2];
    #pragma unroll
    for (int a = 0; a < 2; ++a)
        #pragma unroll
        for (int b = 0; b < 2; ++b)
            acc[a][b] = (f32x4){0.f, 0.f, 0.f, 0.f};

    for (int ch = 0; ch < 1024 / BKC; ++ch) {
        const int k0 = ch * BKC;
        __syncthreads();
        #pragma unroll
        for (int jj = 0; jj < 4; ++jj) {
            const int idx = jj * 256 + tid;
            const int r = idx >> 4, s = idx & 15;
            const int d = (r << 8) + ((s << 4) ^ ((r & 15) << 4));
            const int gA = nb * 64 + r;
            {
                const size_t off = (size_t)gA * 1024 + k0 + s * 8;
                *(uint4*)(sA[0] + d) = *(const uint4*)(Ah + off);
                *(uint4*)(sA[1] + d) = *(const uint4*)(Al + off);
            }
            {
                const size_t off = (size_t)(c0 + r) * 1024 + k0 + s * 8;
                *(uint4*)(sB[0] + d) = *(const uint4*)(Bh + off);
                *(uint4*)(sB[1] + d) = *(const uint4*)(Bl + off);
            }
        }
        __syncthreads();
        #pragma unroll
        for (int ks = 0; ks < 4; ++ks) {
            const int kb = ks * 64 + ((lane >> 4) << 4);
            bf16x8 afr[2][2], bfr[2][2];
            #pragma unroll
            for (int rt = 0; rt < 2; ++rt) {
                const int row = wr * 32 + rt * 16 + (lane & 15);
                const int d = (row << 8) + (kb ^ ((row & 15) << 4));
                afr[rt][0] = *(const bf16x8*)(sA[0] + d);
                afr[rt][1] = *(const bf16x8*)(sA[1] + d);
            }
            #pragma unroll
            for (int ct = 0; ct < 2; ++ct) {
                const int row = wc * 32 + ct * 16 + (lane & 15);
                const int d = (row << 8) + (kb ^ ((row & 15) << 4));
                bfr[ct][0] = *(const bf16x8*)(sB[0] + d);
                bfr[ct][1] = *(const bf16x8*)(sB[1] + d);
            }
            #pragma unroll
            for (int rt = 0; rt < 2; ++rt)
                #pragma unroll
                for (int ct = 0; ct < 2; ++ct) {
                    acc[rt][ct] = __builtin_amdgcn_mfma_f32_16x16x32_bf16(afr[rt][0], bfr[ct][0], acc[rt][ct], 0, 0, 0);
                    acc[rt][ct] = __builtin_amdgcn_mfma_f32_16x16x32_bf16(afr[rt][0], bfr[ct][1], acc[rt][ct], 0, 0, 0);
                    acc[rt][ct] = __builtin_amdgcn_mfma_f32_16x16x32_bf16(afr[rt][1], bfr[ct][0], acc[rt][ct], 0, 0, 0);
                }
        }
    }

    #pragma unroll
    for (int rt = 0; rt < 2; ++rt)
        #pragma unroll
        for (int ct = 0; ct < 2; ++ct)
            #pragma unroll
            for (int r = 0; r < 4; ++r) {
                const int row = wr * 32 + rt * 16 + ((lane >> 4) << 2) + r;
                const int col = wc * 32 + ct * 16 + (lane & 15);
                const float v = acc[rt][ct][r];
                if (MODE == 0) {
                    const size_t o = (size_t)(nb * 64 + row) * 1024 + c0 + col;
                    const __bf16 h = (__bf16)v;
                    Oh[o] = h;
                    Ol[o] = (__bf16)(v - (float)h);
                } else {
                    SX[(size_t)(nb * 64 + row) * 256 + c0 + col] = v;
                }
            }
}

__global__ __launch_bounds__(1024) void split_S(const float* __restrict__ S,
    __bf16* __restrict__ Ah, __bf16* __restrict__ Al,
    __bf16* __restrict__ STh, __bf16* __restrict__ STl)
{
    __shared__ float tile[32][33];
    const int tx = threadIdx.x & 31, ty = threadIdx.x >> 5;
    const int r0 = blockIdx.y * 32, c0 = blockIdx.x * 32;
    const float v = S[(size_t)(r0 + ty) * 1024 + c0 + tx];
    tile[ty][tx] = v;
    {
        const __bf16 h = (__bf16)v;
        const size_t o = (size_t)(r0 + ty) * 1024 + c0 + tx;
        Ah[o] = h; Al[o] = (__bf16)(v - (float)h);
    }
    __syncthreads();
    const float wv = tile[tx][ty];
    const __bf16 h = (__bf16)wv;
    const size_t o = (size_t)(c0 + ty) * 1024 + r0 + tx;
    STh[o] = h; STl[o] = (__bf16)(wv - (float)h);
}

// row-major split planes -> AF fragment layout
__global__ __launch_bounds__(256) void repackAF2(const __bf16* __restrict__ rmh,
    const __bf16* __restrict__ rml, __bf16* __restrict__ AF)
{
    const int g = blockIdx.x * 256 + threadIdx.x;
    const int row = g >> 7;
    const int k0 = (g & 127) * 8;
    const int p = row >> 10, n = row & 1023;
    const int nb = n >> 4, i = n & 15;
    const int kblk = k0 >> 5, khi = (k0 >> 3) & 3;
    const size_t off = ((size_t)nb * 32 + kblk) * 4096 + p * 512 + (i + 16 * khi) * 8;
    *(bf16x8*)(AF + off)        = *(const bf16x8*)(rmh + (size_t)row * 1024 + k0);
    *(bf16x8*)(AF + off + 2048) = *(const bf16x8*)(rml + (size_t)row * 1024 + k0);
}

__global__ __launch_bounds__(256) void init_x0(const float* __restrict__ x0,
    float* __restrict__ SX, float* __restrict__ x_traj,
    __bf16* __restrict__ X0Th, __bf16* __restrict__ X0Tl)
{
    const int g = blockIdx.x * 256 + threadIdx.x;
    const int b = g >> 10, n = g & 1023;
    const f32x4 v = *(const f32x4*)(x0 + (size_t)g * 4);
    *(f32x4*)(SX + (size_t)n * 256 + b * 4) = v;
    *(f32x4*)(x_traj + (size_t)b * ((T_STEPS + 1) * 4096) + n * 4) = v;
    #pragma unroll
    for (int p = 0; p < 4; ++p) {
        const __bf16 h = (__bf16)v[p];
        const size_t o = (size_t)(b * 4 + p) * 1024 + n;
        X0Th[o] = h; X0Tl[o] = (__bf16)(v[p] - (float)h);
    }
}

__global__ __launch_bounds__(256) void w0_kernel(const float* __restrict__ SX,
    const float* __restrict__ H1, const float* __restrict__ H2,
    __bf16* __restrict__ WFh, __bf16* __restrict__ WFl)
{
    __shared__ float h1s[512], h2s[128];
    const int tid = threadIdx.x;
    for (int i2 = tid; i2 < 512; i2 += 256) h1s[i2] = H1[i2];
    if (tid < 128) h2s[tid] = H2[tid];
    __syncthreads();
    const int g = blockIdx.x * 256 + tid;
    const int b = g >> 10, n = g & 1023;
    float sx[16];
    #pragma unroll
    for (int k = 0; k < 4; ++k) {
        const f32x4 v = *(const f32x4*)(SX + (size_t)(k * NN + n) * 256 + b * 4);
        #pragma unroll
        for (int q = 0; q < 4; ++q) sx[k * 4 + q] = v[q];
    }
    float w4[4] = {0.f, 0.f, 0.f, 0.f};
    #pragma unroll 4
    for (int f = 0; f < 32; ++f) {
        float z = 0.f;
        #pragma unroll
        for (int kp = 0; kp < 16; ++kp) z = fmaf(sx[kp], h1s[kp * 32 + f], z);
        z = fast_tanh(z);
        #pragma unroll
        for (int q = 0; q < 4; ++q) w4[q] = fmaf(z, h2s[f * 4 + q], w4[q]);
    }
    const int kblkw = n >> 5;
    const int lhi = ((n >> 3) & 3) << 4;
    const int jw = n & 7;
    #pragma unroll
    for (int q = 0; q < 4; ++q) {
        const int col = b * 4 + q;
        const size_t o = ((size_t)(col >> 4) * 32 + kblkw) * 512 + ((col & 15) + lhi) * 8 + jw;
        const __bf16 h = (__bf16)w4[q];
        WFh[o] = h;
        WFl[o] = (__bf16)(w4[q] - (float)h);
    }
}

extern "C" void kernel_launch(void* const* d_in, const int* in_sizes, int n_in,
                              void* d_out, int out_size, void* d_ws, size_t ws_size,
                              hipStream_t stream)
{
    const float* x0 = (const float*)d_in[0];
    const float* S  = (const float*)d_in[1];
    const float* H1 = (const float*)d_in[2];
    const float* H2 = (const float*)d_in[3];

    float* x_traj = (float*)d_out;
    float* u_traj = x_traj + (size_t)64 * (T_STEPS + 1) * NN * 4;

    // workspace carve (38 MB)
    char* w = (char*)d_ws;
    __bf16* Ah_rm = (__bf16*)(w);                    // 8 MB [setup only]
    __bf16* Al_rm = (__bf16*)(w + (8u << 20));       // 8 MB [setup only]
    __bf16* AF    = (__bf16*)(w + (16u << 20));      // 16 MB fragment-order A
    float*  SX    = (float*) (w + (32u << 20));      // 4 MB
    __bf16* WF0h  = (__bf16*)(w + (36u << 20));                  // 512 KB
    __bf16* WF0l  = (__bf16*)(w + (36u << 20) + (512u << 10));   // 512 KB
    __bf16* WF1h  = (__bf16*)(w + (37u << 20));                  // 512 KB
    __bf16* WF1l  = (__bf16*)(w + (37u << 20) + (512u << 10));   // 512 KB
    // setup-only aliases
    __bf16* STh   = AF;                              // dead before repackAF2
    __bf16* STl   = AF + (size_t)1024 * 1024;
    __bf16* X0Th  = WF1h;                            // dead before step 0 writes
    __bf16* X0Tl  = WF1l;

    dim3 blk(256);

    // 1) split S -> row-major split planes + S^T split planes
    split_S<<<dim3(32, 32), 1024, 0, stream>>>(S, Ah_rm, Al_rm, STh, STl);

    // 2) power chain: S^{j+1} = S^j @ S (full 3-term precision)
    for (int jj = 1; jj <= 3; ++jj) {
        gemm_core<0><<<dim3(16, 16), blk, 0, stream>>>(
            Ah_rm + (size_t)(jj - 1) * 1024 * 1024, Al_rm + (size_t)(jj - 1) * 1024 * 1024,
            STh, STl,
            Ah_rm + (size_t)jj * 1024 * 1024, Al_rm + (size_t)jj * 1024 * 1024, nullptr);
    }

    // 3) SX_0 = x0, x_traj[:,0], x0^T split planes (into WF1 aliases)
    init_x0<<<dim3(256), blk, 0, stream>>>(x0, SX, x_traj, X0Th, X0Tl);

    // 4) SX_{1..3} = [S;S^2;S^3] @ x0
    gemm_core<1><<<dim3(4, 48), blk, 0, stream>>>(
        Ah_rm, Al_rm, X0Th, X0Tl, nullptr, nullptr, SX + (size_t)1024 * 256);

    // 5) repack row-major -> fragment layout (clobbers ST alias; after chain)
    repackAF2<<<dim3(2048), blk, 0, stream>>>(Ah_rm, Al_rm, AF);

    // 6) W_0 -> WF0 planes
    w0_kernel<<<dim3(256), blk, 0, stream>>>(SX, H1, H2, WF0h, WF0l);

    // 7) rollout: one fused kernel per step, W ping-pong (t=0 reads WF0)
    for (int t = 0; t < T_STEPS; ++t) {
        const __bf16* rh = (t & 1) ? WF1h : WF0h;
        const __bf16* rl = (t & 1) ? WF1l : WF0l;
        __bf16* oh = (t & 1) ? WF0h : WF1h;
        __bf16* ol = (t & 1) ? WF0l : WF1l;
        step_kernel<<<dim3(256), dim3(512), 0, stream>>>(
            AF, rh, rl, oh, ol, SX, x_traj, u_traj, H1, H2, t);
    }
}

// Round 11
// 938.178 us; speedup vs baseline: 2.0937x; 1.3738x over previous
//
#include <hip/hip_runtime.h>

#define T_STEPS 64
#define NN 1024
#define BKC 128

typedef __bf16 bf16x8 __attribute__((ext_vector_type(8)));
typedef float f32x4 __attribute__((ext_vector_type(4)));

__device__ __forceinline__ float fast_tanh(float z) {
    z = fminf(15.f, fmaxf(-15.f, z));
    const float t = __builtin_amdgcn_exp2f(z * 2.8853900817779268f);  // e^{2z}
    return (t - 1.f) * __builtin_amdgcn_rcpf(t + 1.f);
}

__device__ __forceinline__ void nt_store4(float* p, f32x4 v) {
    __builtin_nontemporal_store(v, (f32x4*)p);
}

// load one kb batch of fragments (16 x b128 from L2)
#define LOAD_KB(kb, ah, al, bh, bl)                                         \
    _Pragma("unroll")                                                       \
    for (int p = 0; p < 4; ++p) {                                           \
        ah[p] = *(const bf16x8*)(Abase + (kb) * 4096 + p * 512);            \
        al[p] = *(const bf16x8*)(Abase + (kb) * 4096 + 2048 + p * 512);     \
    }                                                                       \
    _Pragma("unroll")                                                       \
    for (int c = 0; c < 4; ++c) {                                           \
        bh[c] = *(const bf16x8*)(Bbaseh + (kb) * 512 + c * 16384);          \
        bl[c] = *(const bf16x8*)(Bbasel + (kb) * 512 + c * 16384);          \
    }

// 48 MFMAs (3-term split product) on one kb batch
#define MFMA_KB(ah, al, bh, bl)                                             \
    _Pragma("unroll")                                                       \
    for (int p = 0; p < 4; ++p)                                             \
        _Pragma("unroll")                                                   \
        for (int c = 0; c < 4; ++c) {                                       \
            acc[p][c] = __builtin_amdgcn_mfma_f32_16x16x32_bf16(ah[p], bh[c], acc[p][c], 0, 0, 0); \
            acc[p][c] = __builtin_amdgcn_mfma_f32_16x16x32_bf16(al[p], bh[c], acc[p][c], 0, 0, 0); \
            acc[p][c] = __builtin_amdgcn_mfma_f32_16x16x32_bf16(ah[p], bl[c], acc[p][c], 0, 0, 0); \
        }

// ===========================================================================
// Per-step fused kernel == R8 verbatim (the proven 944 us structure: 8-way
// K-split is the unique wave decomposition ingesting A and B exactly once
// per block — R10's col-split quadrupled A traffic, +5.4 us/step measured ==
// model's +5.7) PLUS nontemporal x/u stores (R9 counters: trajectory writes
// evicted A from L2, 3.8 MB/step refetch).
// ===========================================================================
__global__ __launch_bounds__(512, 1) void step_kernel(
    const __bf16* __restrict__ AF,
    const __bf16* __restrict__ WFh, const __bf16* __restrict__ WFl,
    __bf16* __restrict__ WFoh, __bf16* __restrict__ WFol,
    float* __restrict__ SX, float* __restrict__ x_traj, float* __restrict__ u_traj,
    const float* __restrict__ H1, const float* __restrict__ H2, int t)
{
    __shared__ __align__(16) float dumps[8][4096];   // 128 KB
    __shared__ float h1s[512];
    __shared__ float h2s[128];

    const int tid  = threadIdx.x;
    const int lane = tid & 63;
    const int w    = tid >> 6;                 // wave 0..7 (K-split)

    h1s[tid & 511] = H1[tid & 511];
    if (tid < 128) h2s[tid] = H2[tid];

    // XCD-aware: each XCD gets 8 nb values x 4 cb -> 2MB A slice L2-resident
    const int l = blockIdx.x;
    const int xcd = l & 7, j = l >> 3;
    const int nb = xcd * 8 + (j & 7);          // 0..63
    const int cb = j >> 3;                     // 0..3

    const __bf16* Abase  = AF  + ((size_t)nb * 32 + w * 4) * 4096 + lane * 8;
    const __bf16* Bbaseh = WFh + ((size_t)(cb * 4) * 32 + w * 4) * 512 + lane * 8;
    const __bf16* Bbasel = WFl + ((size_t)(cb * 4) * 32 + w * 4) * 512 + lane * 8;

    f32x4 acc[4][4];
    #pragma unroll
    for (int p = 0; p < 4; ++p)
        #pragma unroll
        for (int c = 0; c < 4; ++c)
            acc[p][c] = (f32x4){0.f, 0.f, 0.f, 0.f};

    // ---- 2-deep register pipeline over 4 kb batches (named bufs) ----
    bf16x8 aAh[4], aAl[4], aBh[4], aBl[4];     // buffer A
    bf16x8 bAh[4], bAl[4], bBh[4], bBl[4];     // buffer B

    LOAD_KB(0, aAh, aAl, aBh, aBl)
    LOAD_KB(1, bAh, bAl, bBh, bBl)
    MFMA_KB(aAh, aAl, aBh, aBl)
    LOAD_KB(2, aAh, aAl, aBh, aBl)
    MFMA_KB(bAh, bAl, bBh, bBl)
    LOAD_KB(3, bAh, bAl, bBh, bBl)
    MFMA_KB(aAh, aAl, aBh, aBl)
    MFMA_KB(bAh, bAl, bBh, bBl)

    // ---- combine wave partials: dump ----
    #pragma unroll
    for (int p = 0; p < 4; ++p)
        #pragma unroll
        for (int c = 0; c < 4; ++c)
            *(f32x4*)&dumps[w][(p * 4 + c) * 256 + lane * 4] = acc[p][c];
    __syncthreads();
    // two-pass reduce, conflict-free (thread sums one f32x4 at tid*4)
    #pragma unroll
    for (int pass = 0; pass < 2; ++pass) {
        const int pos = pass * 2048 + tid * 4;
        f32x4 s = *(const f32x4*)&dumps[0][pos];
        #pragma unroll
        for (int w2 = 1; w2 < 8; ++w2)
            s += *(const f32x4*)&dumps[w2][pos];
        *(f32x4*)&dumps[0][pos] = s;
    }
    __syncthreads();

    // ---- epilogue on first 256 threads ----
    if (tid < 256) {
        const int i  = tid & 15;       // node-local
        const int bl2 = tid >> 4;      // batch-local (0..15)
        const int n  = nb * 16 + i;
        const int bg = cb * 16 + bl2;
        const int rc = bl2 >> 2;
        const int lidx = ((i >> 2) << 4) + (bl2 & 3) * 4;
        const int rr = i & 3;

        float nv[4][4];
        f32x4 xv, uv;
        #pragma unroll
        for (int p = 0; p < 4; ++p) {
            f32x4 inc;
            #pragma unroll
            for (int q = 0; q < 4; ++q)
                inc[q] = dumps[0][(p * 4 + rc) * 256 + (lidx + q) * 4 + rr];
            const size_t so = (size_t)(p * NN + n) * 256 + bg * 4;
            f32x4 old = *(const f32x4*)(SX + so);
            f32x4 nw;
            #pragma unroll
            for (int q = 0; q < 4; ++q) nw[q] = fmaf(0.1f, inc[q], old[q]);
            *(f32x4*)(SX + so) = nw;
            #pragma unroll
            for (int q = 0; q < 4; ++q) nv[p][q] = nw[q];
            if (p == 0) { xv = nw; uv = inc; }
        }
        nt_store4(x_traj + ((size_t)bg * (T_STEPS + 1) + t + 1) * 4096 + n * 4, xv);
        nt_store4(u_traj + ((size_t)bg * T_STEPS + t) * 4096 + n * 4, uv);

        float w4[4] = {0.f, 0.f, 0.f, 0.f};
        #pragma unroll 4
        for (int f = 0; f < 32; ++f) {
            float z = 0.f;
            #pragma unroll
            for (int k = 0; k < 4; ++k)
                #pragma unroll
                for (int q = 0; q < 4; ++q)
                    z = fmaf(nv[k][q], h1s[(k * 4 + q) * 32 + f], z);
            z = fast_tanh(z);
            #pragma unroll
            for (int q = 0; q < 4; ++q) w4[q] = fmaf(z, h2s[f * 4 + q], w4[q]);
        }
        // W -> fragment order, split hi/lo planes
        const int kblkw = n >> 5;
        const int lhi = ((n >> 3) & 3) << 4;
        const int jw = n & 7;
        #pragma unroll
        for (int q = 0; q < 4; ++q) {
            const int col = bg * 4 + q;
            const size_t o = ((size_t)(col >> 4) * 32 + kblkw) * 512 + ((col & 15) + lhi) * 8 + jw;
            const __bf16 h = (__bf16)w4[q];
            WFoh[o] = h;
            WFol[o] = (__bf16)(w4[q] - (float)h);
        }
    }
}

// ===========================================================================
// Setup kernels (proven R2-R8, unchanged)
// ===========================================================================
template<int MODE>
__global__ __launch_bounds__(256) void gemm_core(
    const __bf16* __restrict__ Ah, const __bf16* __restrict__ Al,
    const __bf16* __restrict__ Bh, const __bf16* __restrict__ Bl,
    __bf16* __restrict__ Oh, __bf16* __restrict__ Ol,
    float* __restrict__ SX)
{
    const int cb = blockIdx.x, nb = blockIdx.y;
    const int c0 = cb * 64;

    __shared__ char sA[2][16384];
    __shared__ char sB[2][16384];

    const int tid = threadIdx.x;
    const int lane = tid & 63;
    const int wid  = tid >> 6;
    const int wr = wid >> 1, wc = wid & 1;

    f32x4 acc[2][2];
    #pragma unroll
    for (int a = 0; a < 2; ++a)
        #pragma unroll
        for (int b = 0; b < 2; ++b)
            acc[a][b] = (f32x4){0.f, 0.f, 0.f, 0.f};

    for (int ch = 0; ch < 1024 / BKC; ++ch) {
        const int k0 = ch * BKC;
        __syncthreads();
        #pragma unroll
        for (int jj = 0; jj < 4; ++jj) {
            const int idx = jj * 256 + tid;
            const int r = idx >> 4, s = idx & 15;
            const int d = (r << 8) + ((s << 4) ^ ((r & 15) << 4));
            const int gA = nb * 64 + r;
            {
                const size_t off = (size_t)gA * 1024 + k0 + s * 8;
                *(uint4*)(sA[0] + d) = *(const uint4*)(Ah + off);
                *(uint4*)(sA[1] + d) = *(const uint4*)(Al + off);
            }
            {
                const size_t off = (size_t)(c0 + r) * 1024 + k0 + s * 8;
                *(uint4*)(sB[0] + d) = *(const uint4*)(Bh + off);
                *(uint4*)(sB[1] + d) = *(const uint4*)(Bl + off);
            }
        }
        __syncthreads();
        #pragma unroll
        for (int ks = 0; ks < 4; ++ks) {
            const int kb = ks * 64 + ((lane >> 4) << 4);
            bf16x8 afr[2][2], bfr[2][2];
            #pragma unroll
            for (int rt = 0; rt < 2; ++rt) {
                const int row = wr * 32 + rt * 16 + (lane & 15);
                const int d = (row << 8) + (kb ^ ((row & 15) << 4));
                afr[rt][0] = *(const bf16x8*)(sA[0] + d);
                afr[rt][1] = *(const bf16x8*)(sA[1] + d);
            }
            #pragma unroll
            for (int ct = 0; ct < 2; ++ct) {
                const int row = wc * 32 + ct * 16 + (lane & 15);
                const int d = (row << 8) + (kb ^ ((row & 15) << 4));
                bfr[ct][0] = *(const bf16x8*)(sB[0] + d);
                bfr[ct][1] = *(const bf16x8*)(sB[1] + d);
            }
            #pragma unroll
            for (int rt = 0; rt < 2; ++rt)
                #pragma unroll
                for (int ct = 0; ct < 2; ++ct) {
                    acc[rt][ct] = __builtin_amdgcn_mfma_f32_16x16x32_bf16(afr[rt][0], bfr[ct][0], acc[rt][ct], 0, 0, 0);
                    acc[rt][ct] = __builtin_amdgcn_mfma_f32_16x16x32_bf16(afr[rt][0], bfr[ct][1], acc[rt][ct], 0, 0, 0);
                    acc[rt][ct] = __builtin_amdgcn_mfma_f32_16x16x32_bf16(afr[rt][1], bfr[ct][0], acc[rt][ct], 0, 0, 0);
                }
        }
    }

    #pragma unroll
    for (int rt = 0; rt < 2; ++rt)
        #pragma unroll
        for (int ct = 0; ct < 2; ++ct)
            #pragma unroll
            for (int r = 0; r < 4; ++r) {
                const int row = wr * 32 + rt * 16 + ((lane >> 4) << 2) + r;
                const int col = wc * 32 + ct * 16 + (lane & 15);
                const float v = acc[rt][ct][r];
                if (MODE == 0) {
                    const size_t o = (size_t)(nb * 64 + row) * 1024 + c0 + col;
                    const __bf16 h = (__bf16)v;
                    Oh[o] = h;
                    Ol[o] = (__bf16)(v - (float)h);
                } else {
                    SX[(size_t)(nb * 64 + row) * 256 + c0 + col] = v;
                }
            }
}

__global__ __launch_bounds__(1024) void split_S(const float* __restrict__ S,
    __bf16* __restrict__ Ah, __bf16* __restrict__ Al,
    __bf16* __restrict__ STh, __bf16* __restrict__ STl)
{
    __shared__ float tile[32][33];
    const int tx = threadIdx.x & 31, ty = threadIdx.x >> 5;
    const int r0 = blockIdx.y * 32, c0 = blockIdx.x * 32;
    const float v = S[(size_t)(r0 + ty) * 1024 + c0 + tx];
    tile[ty][tx] = v;
    {
        const __bf16 h = (__bf16)v;
        const size_t o = (size_t)(r0 + ty) * 1024 + c0 + tx;
        Ah[o] = h; Al[o] = (__bf16)(v - (float)h);
    }
    __syncthreads();
    const float wv = tile[tx][ty];
    const __bf16 h = (__bf16)wv;
    const size_t o = (size_t)(c0 + ty) * 1024 + r0 + tx;
    STh[o] = h; STl[o] = (__bf16)(wv - (float)h);
}

// row-major split planes -> AF fragment layout
__global__ __launch_bounds__(256) void repackAF2(const __bf16* __restrict__ rmh,
    const __bf16* __restrict__ rml, __bf16* __restrict__ AF)
{
    const int g = blockIdx.x * 256 + threadIdx.x;
    const int row = g >> 7;
    const int k0 = (g & 127) * 8;
    const int p = row >> 10, n = row & 1023;
    const int nb = n >> 4, i = n & 15;
    const int kblk = k0 >> 5, khi = (k0 >> 3) & 3;
    const size_t off = ((size_t)nb * 32 + kblk) * 4096 + p * 512 + (i + 16 * khi) * 8;
    *(bf16x8*)(AF + off)        = *(const bf16x8*)(rmh + (size_t)row * 1024 + k0);
    *(bf16x8*)(AF + off + 2048) = *(const bf16x8*)(rml + (size_t)row * 1024 + k0);
}

__global__ __launch_bounds__(256) void init_x0(const float* __restrict__ x0,
    float* __restrict__ SX, float* __restrict__ x_traj,
    __bf16* __restrict__ X0Th, __bf16* __restrict__ X0Tl)
{
    const int g = blockIdx.x * 256 + threadIdx.x;
    const int b = g >> 10, n = g & 1023;
    const f32x4 v = *(const f32x4*)(x0 + (size_t)g * 4);
    *(f32x4*)(SX + (size_t)n * 256 + b * 4) = v;
    *(f32x4*)(x_traj + (size_t)b * ((T_STEPS + 1) * 4096) + n * 4) = v;
    #pragma unroll
    for (int p = 0; p < 4; ++p) {
        const __bf16 h = (__bf16)v[p];
        const size_t o = (size_t)(b * 4 + p) * 1024 + n;
        X0Th[o] = h; X0Tl[o] = (__bf16)(v[p] - (float)h);
    }
}

__global__ __launch_bounds__(256) void w0_kernel(const float* __restrict__ SX,
    const float* __restrict__ H1, const float* __restrict__ H2,
    __bf16* __restrict__ WFh, __bf16* __restrict__ WFl)
{
    __shared__ float h1s[512], h2s[128];
    const int tid = threadIdx.x;
    for (int i2 = tid; i2 < 512; i2 += 256) h1s[i2] = H1[i2];
    if (tid < 128) h2s[tid] = H2[tid];
    __syncthreads();
    const int g = blockIdx.x * 256 + tid;
    const int b = g >> 10, n = g & 1023;
    float sx[16];
    #pragma unroll
    for (int k = 0; k < 4; ++k) {
        const f32x4 v = *(const f32x4*)(SX + (size_t)(k * NN + n) * 256 + b * 4);
        #pragma unroll
        for (int q = 0; q < 4; ++q) sx[k * 4 + q] = v[q];
    }
    float w4[4] = {0.f, 0.f, 0.f, 0.f};
    #pragma unroll 4
    for (int f = 0; f < 32; ++f) {
        float z = 0.f;
        #pragma unroll
        for (int kp = 0; kp < 16; ++kp) z = fmaf(sx[kp], h1s[kp * 32 + f], z);
        z = fast_tanh(z);
        #pragma unroll
        for (int q = 0; q < 4; ++q) w4[q] = fmaf(z, h2s[f * 4 + q], w4[q]);
    }
    const int kblkw = n >> 5;
    const int lhi = ((n >> 3) & 3) << 4;
    const int jw = n & 7;
    #pragma unroll
    for (int q = 0; q < 4; ++q) {
        const int col = b * 4 + q;
        const size_t o = ((size_t)(col >> 4) * 32 + kblkw) * 512 + ((col & 15) + lhi) * 8 + jw;
        const __bf16 h = (__bf16)w4[q];
        WFh[o] = h;
        WFl[o] = (__bf16)(w4[q] - (float)h);
    }
}

extern "C" void kernel_launch(void* const* d_in, const int* in_sizes, int n_in,
                              void* d_out, int out_size, void* d_ws, size_t ws_size,
                              hipStream_t stream)
{
    const float* x0 = (const float*)d_in[0];
    const float* S  = (const float*)d_in[1];
    const float* H1 = (const float*)d_in[2];
    const float* H2 = (const float*)d_in[3];

    float* x_traj = (float*)d_out;
    float* u_traj = x_traj + (size_t)64 * (T_STEPS + 1) * NN * 4;

    // workspace carve (38 MB)
    char* w = (char*)d_ws;
    __bf16* Ah_rm = (__bf16*)(w);                    // 8 MB [setup only]
    __bf16* Al_rm = (__bf16*)(w + (8u << 20));       // 8 MB [setup only]
    __bf16* AF    = (__bf16*)(w + (16u << 20));      // 16 MB fragment-order A
    float*  SX    = (float*) (w + (32u << 20));      // 4 MB
    __bf16* WF0h  = (__bf16*)(w + (36u << 20));                  // 512 KB
    __bf16* WF0l  = (__bf16*)(w + (36u << 20) + (512u << 10));   // 512 KB
    __bf16* WF1h  = (__bf16*)(w + (37u << 20));                  // 512 KB
    __bf16* WF1l  = (__bf16*)(w + (37u << 20) + (512u << 10));   // 512 KB
    // setup-only aliases
    __bf16* STh   = AF;                              // dead before repackAF2
    __bf16* STl   = AF + (size_t)1024 * 1024;
    __bf16* X0Th  = WF1h;                            // dead before step 0 writes
    __bf16* X0Tl  = WF1l;

    dim3 blk(256);

    // 1) split S -> row-major split planes + S^T split planes
    split_S<<<dim3(32, 32), 1024, 0, stream>>>(S, Ah_rm, Al_rm, STh, STl);

    // 2) power chain: S^{j+1} = S^j @ S (full 3-term precision)
    for (int jj = 1; jj <= 3; ++jj) {
        gemm_core<0><<<dim3(16, 16), blk, 0, stream>>>(
            Ah_rm + (size_t)(jj - 1) * 1024 * 1024, Al_rm + (size_t)(jj - 1) * 1024 * 1024,
            STh, STl,
            Ah_rm + (size_t)jj * 1024 * 1024, Al_rm + (size_t)jj * 1024 * 1024, nullptr);
    }

    // 3) SX_0 = x0, x_traj[:,0], x0^T split planes (into WF1 aliases)
    init_x0<<<dim3(256), blk, 0, stream>>>(x0, SX, x_traj, X0Th, X0Tl);

    // 4) SX_{1..3} = [S;S^2;S^3] @ x0
    gemm_core<1><<<dim3(4, 48), blk, 0, stream>>>(
        Ah_rm, Al_rm, X0Th, X0Tl, nullptr, nullptr, SX + (size_t)1024 * 256);

    // 5) repack row-major -> fragment layout (clobbers ST alias; after chain)
    repackAF2<<<dim3(2048), blk, 0, stream>>>(Ah_rm, Al_rm, AF);

    // 6) W_0 -> WF0 planes
    w0_kernel<<<dim3(256), blk, 0, stream>>>(SX, H1, H2, WF0h, WF0l);

    // 7) rollout: one fused kernel per step, W ping-pong (t=0 reads WF0)
    for (int t = 0; t < T_STEPS; ++t) {
        const __bf16* rh = (t & 1) ? WF1h : WF0h;
        const __bf16* rl = (t & 1) ? WF1l : WF0l;
        __bf16* oh = (t & 1) ? WF0h : WF1h;
        __bf16* ol = (t & 1) ? WF0l : WF1l;
        step_kernel<<<dim3(256), dim3(512), 0, stream>>>(
            AF, rh, rl, oh, ol, SX, x_traj, u_traj, H1, H2, t);
    }
}